// Round 1
// 569.797 us; speedup vs baseline: 1.1956x; 1.1956x over previous
//
#include <hip/hip_runtime.h>
#include <stdint.h>

#define ATO 32000
#define SCO 1000
#define VQ_START 33100
#define VQ_END 49484
#define EMB_D 2048
#define VQ_K 256
#define NSPLIT 8                       // img_proj N-dimension split factor
#define NCOLS_PER_BLOCK (EMB_D / NSPLIT)   // 256 cols per block, 4 LDS chunks

typedef __bf16 bf16_t;
typedef bf16_t bf16x8 __attribute__((ext_vector_type(8)));
typedef float floatx4 __attribute__((ext_vector_type(4)));
typedef float f32x4v __attribute__((ext_vector_type(4)));

// ---------------------------------------------------------------------------
// Tiny capture-safe zeroing kernel (replaces hipMemsetAsync on d_ws).
// ---------------------------------------------------------------------------
__global__ void zero_count_kernel(int* __restrict__ c) {
    if (threadIdx.x == 0) *c = 0;
}

// ---------------------------------------------------------------------------
// Kernel 1: one WAVE per token (4 tokens / 256-thread block).
// Non-image tokens: copy the 8 KiB embedding row as 8 independent float4
// loads per lane (one base address + immediate offsets -> 8 loads in flight,
// vs 2 in the previous version), then 8 nontemporal float4 stores (streaming
// output should not thrash L2 ahead of the GEMM's codebook/proj_w reads).
// Image tokens: lane 0 compacts (pos | img_idx<<18) via device-scope atomic.
// ---------------------------------------------------------------------------
__global__ __launch_bounds__(256, 8) void gather_compact_kernel(
    const int* __restrict__ x,
    const float* __restrict__ token_emb,
    const float* __restrict__ added_emb,
    const float* __restrict__ numbers_emb,
    float* __restrict__ out,
    int* __restrict__ img_count,
    unsigned int* __restrict__ img_list,
    int n_tok)
{
    const int wave = threadIdx.x >> 6;
    const int lane = threadIdx.x & 63;
    const int t = blockIdx.x * 4 + wave;
    if (t >= n_tok) return;

    const int v = x[t];                      // wave-uniform (broadcast load)
    const float* src = nullptr;
    if (v >= 0 && v < ATO) {
        src = token_emb + (size_t)v * EMB_D;
    } else if (v >= ATO && v < ATO + SCO) {
        src = numbers_emb + (size_t)(v - ATO) * EMB_D;
    } else if (v >= ATO + SCO && v < VQ_START) {
        src = added_emb + (size_t)(v - ATO - SCO) * EMB_D;
    } else if (v >= VQ_START && v < VQ_END) {
        if (lane == 0) {
            const int slot = atomicAdd(img_count, 1);
            img_list[slot] = (unsigned int)t | ((unsigned int)(v - VQ_START) << 18);
        }
        return;
    }

    f32x4v* d4 = (f32x4v*)(out + (size_t)t * EMB_D);
    if (src) {
        const f32x4v* s4 = (const f32x4v*)src;
        f32x4v r[8];
#pragma unroll
        for (int j = 0; j < 8; ++j) r[j] = s4[lane + 64 * j];   // 8 loads in flight
#pragma unroll
        for (int j = 0; j < 8; ++j)
            __builtin_nontemporal_store(r[j], &d4[lane + 64 * j]);
    } else {
        // out-of-range token id: all masks false in the reference -> zeros
        const f32x4v z = {0.f, 0.f, 0.f, 0.f};
#pragma unroll
        for (int j = 0; j < 8; ++j)
            __builtin_nontemporal_store(z, &d4[lane + 64 * j]);
    }
}

// ---------------------------------------------------------------------------
// Kernel 2: dense GEMM over compacted image tokens.
//   C[m, n] = sum_k codebook[idx_m, k] * proj_w[n, k]   (both K-major)
// Block tile: M=64 tokens, K=256 fully in registers (A split bf16 hi/lo),
// N = 256-col slice selected by blockIdx.y (NSPLIT=8), looped in chunks of
// 64 staged in LDS (proj_w fp32 -> bf16 hi/lo, XOR-swizzled 16B groups).
// Split-bf16 product: hi*hi + hi*lo + lo*hi ~= fp32 accuracy (~2^-17 rel).
// Wave tiling: 4 waves in 2x2 grid, each wave 32m x 32n via 16x16x32 MFMA.
//
// Rationale for blockIdx.y split: with M=64 only ~170 m-groups are active
// (~10.9K image tokens) on 256 CUs -> launch-width bound (Occupancy 8%,
// MfmaUtil 6%). x8 split gives ~1360 active blocks; the A-fragment reload
// per slice is L3-resident codebook traffic (16.7 MB table).
// ---------------------------------------------------------------------------
__global__ __launch_bounds__(256, 1) void img_proj_kernel(
    const float* __restrict__ codebook,
    const float* __restrict__ proj_w,
    float* __restrict__ out,
    const int* __restrict__ img_count,
    const unsigned int* __restrict__ img_list)
{
    __shared__ bf16_t w_hi[64 * 32 * 8];   // 32 KiB
    __shared__ bf16_t w_lo[64 * 32 * 8];   // 32 KiB
    __shared__ unsigned int toks[64];

    const int count  = *img_count;
    const int m_base = blockIdx.x * 64;
    if (m_base >= count) return;           // uniform early-exit (inactive block)

    const int tid    = threadIdx.x;
    const int lane   = tid & 63;
    const int wave   = tid >> 6;
    const int wave_m = wave >> 1;          // 0/1 -> m half
    const int wave_n = wave & 1;           // 0/1 -> n half of the 64-chunk
    const int l15    = lane & 15;
    const int quad   = lane >> 4;
    const int nc0    = blockIdx.y * NCOLS_PER_BLOCK;

    if (tid < 64) {
        int mg = m_base + tid;
        if (mg >= count) mg = count - 1;   // clamp ragged tail (stores guarded)
        toks[tid] = img_list[mg];
    }
    __syncthreads();

    // ---- A fragments: 32 rows per wave, full K=256, split hi/lo ----
    // A layout for mfma_f32_16x16x32_bf16: lane holds A[m=lane&15][k=quad*8+j]
    bf16x8 a_hi[2][8], a_lo[2][8];
#pragma unroll
    for (int msub = 0; msub < 2; ++msub) {
        const unsigned int pk = toks[wave_m * 32 + msub * 16 + l15];
        const int row = (int)(pk >> 18);
        const float* arow = codebook + (size_t)row * VQ_K;
#pragma unroll
        for (int kk = 0; kk < 8; ++kk) {
            const float4* p = (const float4*)(arow + kk * 32 + quad * 8);
            const float4 f0 = p[0];
            const float4 f1 = p[1];
            const float f[8] = {f0.x, f0.y, f0.z, f0.w, f1.x, f1.y, f1.z, f1.w};
            bf16x8 h, l;
#pragma unroll
            for (int j = 0; j < 8; ++j) {
                const bf16_t hb = (bf16_t)f[j];
                h[j] = hb;
                l[j] = (bf16_t)(f[j] - (float)hb);
            }
            a_hi[msub][kk] = h;
            a_lo[msub][kk] = l;
        }
    }

    const floatx4 vzero = {0.f, 0.f, 0.f, 0.f};

    for (int nc = nc0; nc < nc0 + NCOLS_PER_BLOCK; nc += 64) {
        __syncthreads();   // previous chunk's LDS reads done before restaging
        // ---- stage proj_w[nc..nc+63][0..255] -> LDS bf16 hi/lo, swizzled ----
#pragma unroll
        for (int it = 0; it < 8; ++it) {
            const int i = tid + it * 256;       // 0..2047 (64 rows x 32 groups)
            const int n = i >> 5;
            const int g = i & 31;
            const float4* p = (const float4*)(proj_w + (size_t)(nc + n) * VQ_K + g * 8);
            const float4 f0 = p[0];
            const float4 f1 = p[1];
            const float f[8] = {f0.x, f0.y, f0.z, f0.w, f1.x, f1.y, f1.z, f1.w};
            bf16x8 h, l;
#pragma unroll
            for (int j = 0; j < 8; ++j) {
                const bf16_t hb = (bf16_t)f[j];
                h[j] = hb;
                l[j] = (bf16_t)(f[j] - (float)hb);
            }
            const int off = (n * 32 + (g ^ (n & 31))) * 8;   // XOR swizzle
            *(bf16x8*)(w_hi + off) = h;
            *(bf16x8*)(w_lo + off) = l;
        }
        __syncthreads();

        floatx4 acc[2][2];
#pragma unroll
        for (int i = 0; i < 2; ++i)
#pragma unroll
            for (int j = 0; j < 2; ++j) acc[i][j] = vzero;

#pragma unroll
        for (int kk = 0; kk < 8; ++kk) {
#pragma unroll
            for (int nsub = 0; nsub < 2; ++nsub) {
                const int n_l = wave_n * 32 + nsub * 16 + l15;
                const int g   = kk * 4 + quad;
                const int off = (n_l * 32 + (g ^ (n_l & 31))) * 8;
                const bf16x8 bh = *(const bf16x8*)(w_hi + off);  // ds_read_b128
                const bf16x8 bl = *(const bf16x8*)(w_lo + off);
#pragma unroll
                for (int msub = 0; msub < 2; ++msub) {
                    acc[msub][nsub] = __builtin_amdgcn_mfma_f32_16x16x32_bf16(
                        a_lo[msub][kk], bh, acc[msub][nsub], 0, 0, 0);
                    acc[msub][nsub] = __builtin_amdgcn_mfma_f32_16x16x32_bf16(
                        a_hi[msub][kk], bl, acc[msub][nsub], 0, 0, 0);
                    acc[msub][nsub] = __builtin_amdgcn_mfma_f32_16x16x32_bf16(
                        a_hi[msub][kk], bh, acc[msub][nsub], 0, 0, 0);
                }
            }
        }

        // ---- epilogue: C/D layout col = lane&15, row = quad*4 + reg ----
#pragma unroll
        for (int msub = 0; msub < 2; ++msub) {
#pragma unroll
            for (int nsub = 0; nsub < 2; ++nsub) {
#pragma unroll
                for (int r = 0; r < 4; ++r) {
                    const int m_local = wave_m * 32 + msub * 16 + quad * 4 + r;
                    if (m_base + m_local < count) {
                        const int tok = (int)(toks[m_local] & 0x3FFFFu);
                        const int col = nc + wave_n * 32 + nsub * 16 + l15;
                        out[(size_t)tok * EMB_D + col] = acc[msub][nsub][r];
                    }
                }
            }
        }
    }
}

// ---------------------------------------------------------------------------
// Fallback (only if ws_size is too small for the compaction list): fully
// fused, workspace-free. Image tokens do a per-block VALU matvec fed from
// L2-resident proj_w. Correct but slow; exists so an undersized workspace
// can never fault the container.
// ---------------------------------------------------------------------------
__global__ __launch_bounds__(256, 4) void fused_fallback_kernel(
    const int* __restrict__ x,
    const float* __restrict__ token_emb,
    const float* __restrict__ added_emb,
    const float* __restrict__ numbers_emb,
    const float* __restrict__ codebook,
    const float* __restrict__ proj_w,
    float* __restrict__ out)
{
    const int t = blockIdx.x;
    const int v = x[t];
    float* orow = out + (size_t)t * EMB_D;

    if (v >= VQ_START && v < VQ_END) {
        __shared__ float cb[VQ_K];
        cb[threadIdx.x] = codebook[(size_t)(v - VQ_START) * VQ_K + threadIdx.x];
        __syncthreads();
#pragma unroll
        for (int j = 0; j < 8; ++j) {
            const int n = threadIdx.x + 256 * j;
            const float* wrow = proj_w + (size_t)n * VQ_K;
            float s = 0.f;
#pragma unroll 4
            for (int k = 0; k < VQ_K; k += 4) {
                const float4 w4 = *(const float4*)(wrow + k);
                s += w4.x * cb[k] + w4.y * cb[k + 1] + w4.z * cb[k + 2] + w4.w * cb[k + 3];
            }
            orow[n] = s;   // coalesced across threads
        }
        return;
    }

    const float* src = nullptr;
    if (v >= 0 && v < ATO)                  src = token_emb + (size_t)v * EMB_D;
    else if (v >= ATO && v < ATO + SCO)     src = numbers_emb + (size_t)(v - ATO) * EMB_D;
    else if (v >= ATO + SCO && v < VQ_START) src = added_emb + (size_t)(v - ATO - SCO) * EMB_D;

    float4* d4 = (float4*)orow;
    if (src) {
        const float4* s4 = (const float4*)src;
        d4[threadIdx.x]       = s4[threadIdx.x];
        d4[threadIdx.x + 256] = s4[threadIdx.x + 256];
    } else {
        const float4 z = make_float4(0.f, 0.f, 0.f, 0.f);
        d4[threadIdx.x]       = z;
        d4[threadIdx.x + 256] = z;
    }
}

// ---------------------------------------------------------------------------
extern "C" void kernel_launch(void* const* d_in, const int* in_sizes, int n_in,
                              void* d_out, int out_size, void* d_ws, size_t ws_size,
                              hipStream_t stream) {
    const int*   x           = (const int*)d_in[0];
    const float* token_emb   = (const float*)d_in[1];
    const float* added_emb   = (const float*)d_in[2];
    const float* numbers_emb = (const float*)d_in[3];
    const float* codebook    = (const float*)d_in[4];
    const float* proj_w      = (const float*)d_in[5];
    float*       out         = (float*)d_out;

    const int n_tok = in_sizes[0];   // B*S = 32768

    const size_t ws_needed = 16 + (size_t)n_tok * sizeof(unsigned int);
    if (d_ws == nullptr || ws_size < ws_needed) {
        // workspace too small: fused, workspace-free fallback
        fused_fallback_kernel<<<n_tok, 256, 0, stream>>>(
            x, token_emb, added_emb, numbers_emb, codebook, proj_w, out);
        return;
    }

    int* img_count         = (int*)d_ws;
    unsigned int* img_list = (unsigned int*)((char*)d_ws + 16);

    // d_ws is re-poisoned to 0xAA before every call: zero the atomic counter
    // with a capture-safe kernel (no runtime memset APIs inside capture).
    zero_count_kernel<<<1, 64, 0, stream>>>(img_count);

    const int gather_blocks = (n_tok + 3) / 4;   // one wave per token
    gather_compact_kernel<<<gather_blocks, 256, 0, stream>>>(
        x, token_emb, added_emb, numbers_emb, out, img_count, img_list, n_tok);

    const int gemm_blocks_m = (n_tok + 63) / 64;   // static worst-case grid
    dim3 gemm_grid(gemm_blocks_m, NSPLIT);
    img_proj_kernel<<<gemm_grid, 256, 0, stream>>>(
        codebook, proj_w, out, img_count, img_list);
}

// Round 2
// 498.059 us; speedup vs baseline: 1.3678x; 1.1440x over previous
//
#include <hip/hip_runtime.h>
#include <stdint.h>

#define ATO 32000
#define SCO 1000
#define VQ_START 33100
#define VQ_END 49484
#define EMB_D 2048
#define VQ_K 256
#define VQ_VOCAB 16384
#define NSPLIT 8                           // img_proj N-dimension split factor
#define NCOLS_PER_BLOCK (EMB_D / NSPLIT)   // 256 cols per block, 4 LDS chunks

typedef __bf16 bf16_t;
typedef bf16_t bf16x8 __attribute__((ext_vector_type(8)));
typedef float floatx4 __attribute__((ext_vector_type(4)));
typedef float f32x4v __attribute__((ext_vector_type(4)));

// ---------------------------------------------------------------------------
// Tiny capture-safe zeroing kernel (replaces hipMemsetAsync on d_ws).
// ---------------------------------------------------------------------------
__global__ void zero_count_kernel(int* __restrict__ c) {
    if (threadIdx.x == 0) *c = 0;
}

// ---------------------------------------------------------------------------
// Prep kernel. Two roles by blockIdx:
//   blocks [0,128): compaction of image tokens from x via wave ballot +
//     one atomicAdd per wave (list order is irrelevant downstream).
//   blocks [128, 128+2304): convert codebook (2048 blocks) and proj_w
//     (256 blocks) fp32 -> bf16 hi/lo planes in workspace, ONCE. This
//     removes all fp32->bf16 split VALU from the GEMM inner loop, where it
//     was re-done per m-block x per n-slice (MfmaUtil 6% culprit).
// ---------------------------------------------------------------------------
#define PREP_COMPACT_BLOCKS 128
#define PREP_CONV_CB 2048      // 16384*256 / 2048 elems-per-block
#define PREP_CONV_PW 256       // 2048*256 / 2048

__global__ __launch_bounds__(256) void prep_kernel(
    const int* __restrict__ x, int n_tok,
    int* __restrict__ img_count, unsigned int* __restrict__ img_list,
    const float* __restrict__ codebook, const float* __restrict__ proj_w,
    bf16_t* __restrict__ cb_hi, bf16_t* __restrict__ cb_lo,
    bf16_t* __restrict__ pw_hi, bf16_t* __restrict__ pw_lo)
{
    const int b = blockIdx.x;
    if (b < PREP_COMPACT_BLOCKS) {
        const int t = b * 256 + threadIdx.x;
        int v = 0;
        bool is_img = false;
        if (t < n_tok) {
            v = x[t];
            is_img = (v >= VQ_START) && (v < VQ_END);
        }
        const unsigned long long m = __ballot(is_img);
        const int lane = threadIdx.x & 63;
        int base = 0;
        if (lane == 0 && m) base = atomicAdd(img_count, __popcll(m));
        base = __shfl(base, 0);
        if (is_img) {
            const int below = __popcll(m & ((1ull << lane) - 1ull));
            img_list[base + below] =
                (unsigned int)t | ((unsigned int)(v - VQ_START) << 18);
        }
        return;
    }

    // conversion role: each block handles 2048 contiguous floats (256 thr x 8)
    const int cbb = b - PREP_COMPACT_BLOCKS;
    const float* src;
    bf16_t* dh;
    bf16_t* dl;
    size_t base_e;
    if (cbb < PREP_CONV_CB) {
        src = codebook; dh = cb_hi; dl = cb_lo;
        base_e = (size_t)cbb * 2048;
    } else {
        src = proj_w; dh = pw_hi; dl = pw_lo;
        base_e = (size_t)(cbb - PREP_CONV_CB) * 2048;
    }
    const size_t e = base_e + (size_t)threadIdx.x * 8;
    const float4 f0 = *(const float4*)(src + e);
    const float4 f1 = *(const float4*)(src + e + 4);
    const float f[8] = {f0.x, f0.y, f0.z, f0.w, f1.x, f1.y, f1.z, f1.w};
    bf16x8 h, l;
#pragma unroll
    for (int j = 0; j < 8; ++j) {
        const bf16_t hb = (bf16_t)f[j];
        h[j] = hb;
        l[j] = (bf16_t)(f[j] - (float)hb);
    }
    *(bf16x8*)(dh + e) = h;
    *(bf16x8*)(dl + e) = l;
}

// ---------------------------------------------------------------------------
// Mega kernel: GEMM blocks and copy blocks co-scheduled in ONE launch so the
// MFMA-bound projection overlaps the HBM-bound row copies (previously serial
// because the GEMM waited on compaction; prep now provides the list).
//
// blocks [0, gemm_total): dense GEMM over compacted image tokens.
//   C[m,n] = sum_k codebook[idx_m,k] * proj_w[n,k]. M-tile 64 tokens,
//   K=256 in registers (pre-split bf16 hi/lo direct loads), N = 256-col
//   slice (blockIdx & 7), chunks of 64 staged in LDS (XOR swizzle).
//   Split-bf16: hi*hi + hi*lo + lo*hi ~= fp32 (~2^-17 rel), unchanged.
// blocks [gemm_total, +copy_blocks): one WAVE per token; non-image tokens
//   copy their 8 KiB row (8 independent float4 loads -> 8 NT stores);
//   image tokens skip (GEMM blocks own those rows); OOR ids write zeros.
// ---------------------------------------------------------------------------
__global__ __launch_bounds__(256, 2) void mega_kernel(
    const int* __restrict__ x,
    const float* __restrict__ token_emb,
    const float* __restrict__ added_emb,
    const float* __restrict__ numbers_emb,
    const bf16_t* __restrict__ cb_hi, const bf16_t* __restrict__ cb_lo,
    const bf16_t* __restrict__ pw_hi, const bf16_t* __restrict__ pw_lo,
    float* __restrict__ out,
    const int* __restrict__ img_count,
    const unsigned int* __restrict__ img_list,
    int n_tok, int gemm_total)
{
    __shared__ bf16_t w_hi[64 * 32 * 8];   // 32 KiB
    __shared__ bf16_t w_lo[64 * 32 * 8];   // 32 KiB
    __shared__ unsigned int toks[64];

    const int tid  = threadIdx.x;
    const int lane = tid & 63;
    const int wave = tid >> 6;

    if (blockIdx.x >= gemm_total) {
        // ---------------- copy role: one wave per token ----------------
        const int t = (blockIdx.x - gemm_total) * 4 + wave;
        if (t >= n_tok) return;
        const int v = x[t];                      // wave-uniform broadcast
        if (v >= VQ_START && v < VQ_END) return; // GEMM writes this row

        const float* src = nullptr;
        if (v >= 0 && v < ATO)                   src = token_emb + (size_t)v * EMB_D;
        else if (v >= ATO && v < ATO + SCO)      src = numbers_emb + (size_t)(v - ATO) * EMB_D;
        else if (v >= ATO + SCO && v < VQ_START) src = added_emb + (size_t)(v - ATO - SCO) * EMB_D;

        f32x4v* d4 = (f32x4v*)(out + (size_t)t * EMB_D);
        if (src) {
            const f32x4v* s4 = (const f32x4v*)src;
            f32x4v r[8];
#pragma unroll
            for (int j = 0; j < 8; ++j) r[j] = s4[lane + 64 * j];  // 8 in flight
#pragma unroll
            for (int j = 0; j < 8; ++j)
                __builtin_nontemporal_store(r[j], &d4[lane + 64 * j]);
        } else {
            const f32x4v z = {0.f, 0.f, 0.f, 0.f};
#pragma unroll
            for (int j = 0; j < 8; ++j)
                __builtin_nontemporal_store(z, &d4[lane + 64 * j]);
        }
        return;
    }

    // -------------------------- GEMM role --------------------------
    const int count  = *img_count;
    const int m_base = (blockIdx.x >> 3) * 64;   // consecutive 8 blocks share A
    if (m_base >= count) return;                 // uniform early-exit

    const int wave_m = wave >> 1;          // 0/1 -> m half
    const int wave_n = wave & 1;           // 0/1 -> n half of the 64-chunk
    const int l15    = lane & 15;
    const int quad   = lane >> 4;
    const int nc0    = (blockIdx.x & 7) * NCOLS_PER_BLOCK;

    if (tid < 64) {
        int mg = m_base + tid;
        if (mg >= count) mg = count - 1;   // clamp ragged tail (stores guarded)
        toks[tid] = img_list[mg];
    }
    __syncthreads();

    // ---- A fragments: 32 rows per wave, full K=256, pre-split hi/lo ----
    // A layout for mfma_f32_16x16x32_bf16: lane holds A[m=lane&15][k=quad*8+j]
    bf16x8 a_hi[2][8], a_lo[2][8];
#pragma unroll
    for (int msub = 0; msub < 2; ++msub) {
        const unsigned int pk = toks[wave_m * 32 + msub * 16 + l15];
        const int row = (int)(pk >> 18);
        const bf16_t* ah = cb_hi + (size_t)row * VQ_K;
        const bf16_t* al = cb_lo + (size_t)row * VQ_K;
#pragma unroll
        for (int kk = 0; kk < 8; ++kk) {
            a_hi[msub][kk] = *(const bf16x8*)(ah + kk * 32 + quad * 8);
            a_lo[msub][kk] = *(const bf16x8*)(al + kk * 32 + quad * 8);
        }
    }

    const floatx4 vzero = {0.f, 0.f, 0.f, 0.f};

    for (int nc = nc0; nc < nc0 + NCOLS_PER_BLOCK; nc += 64) {
        __syncthreads();   // previous chunk's LDS reads done before restaging
        // ---- stage pre-split proj_w rows -> LDS, XOR-swizzled 16B groups ----
#pragma unroll
        for (int it = 0; it < 8; ++it) {
            const int i = tid + it * 256;       // 0..2047 (64 rows x 32 groups)
            const int n = i >> 5;
            const int g = i & 31;
            const size_t ge = (size_t)(nc + n) * VQ_K + g * 8;
            const bf16x8 h = *(const bf16x8*)(pw_hi + ge);
            const bf16x8 l = *(const bf16x8*)(pw_lo + ge);
            const int off = (n * 32 + (g ^ (n & 31))) * 8;   // XOR swizzle
            *(bf16x8*)(w_hi + off) = h;
            *(bf16x8*)(w_lo + off) = l;
        }
        __syncthreads();

        floatx4 acc[2][2];
#pragma unroll
        for (int i = 0; i < 2; ++i)
#pragma unroll
            for (int j = 0; j < 2; ++j) acc[i][j] = vzero;

#pragma unroll
        for (int kk = 0; kk < 8; ++kk) {
#pragma unroll
            for (int nsub = 0; nsub < 2; ++nsub) {
                const int n_l = wave_n * 32 + nsub * 16 + l15;
                const int g   = kk * 4 + quad;
                const int off = (n_l * 32 + (g ^ (n_l & 31))) * 8;
                const bf16x8 bh = *(const bf16x8*)(w_hi + off);  // ds_read_b128
                const bf16x8 bl = *(const bf16x8*)(w_lo + off);
#pragma unroll
                for (int msub = 0; msub < 2; ++msub) {
                    acc[msub][nsub] = __builtin_amdgcn_mfma_f32_16x16x32_bf16(
                        a_lo[msub][kk], bh, acc[msub][nsub], 0, 0, 0);
                    acc[msub][nsub] = __builtin_amdgcn_mfma_f32_16x16x32_bf16(
                        a_hi[msub][kk], bl, acc[msub][nsub], 0, 0, 0);
                    acc[msub][nsub] = __builtin_amdgcn_mfma_f32_16x16x32_bf16(
                        a_hi[msub][kk], bh, acc[msub][nsub], 0, 0, 0);
                }
            }
        }

        // ---- epilogue: C/D layout col = lane&15, row = quad*4 + reg ----
#pragma unroll
        for (int msub = 0; msub < 2; ++msub) {
#pragma unroll
            for (int nsub = 0; nsub < 2; ++nsub) {
#pragma unroll
                for (int r = 0; r < 4; ++r) {
                    const int m_local = wave_m * 32 + msub * 16 + quad * 4 + r;
                    if (m_base + m_local < count) {
                        const int tok = (int)(toks[m_local] & 0x3FFFFu);
                        const int col = nc + wave_n * 32 + nsub * 16 + l15;
                        out[(size_t)tok * EMB_D + col] = acc[msub][nsub][r];
                    }
                }
            }
        }
    }
}

// ---------------------------------------------------------------------------
// Fallback (only if ws_size is too small): fully fused, workspace-free.
// ---------------------------------------------------------------------------
__global__ __launch_bounds__(256, 4) void fused_fallback_kernel(
    const int* __restrict__ x,
    const float* __restrict__ token_emb,
    const float* __restrict__ added_emb,
    const float* __restrict__ numbers_emb,
    const float* __restrict__ codebook,
    const float* __restrict__ proj_w,
    float* __restrict__ out)
{
    const int t = blockIdx.x;
    const int v = x[t];
    float* orow = out + (size_t)t * EMB_D;

    if (v >= VQ_START && v < VQ_END) {
        __shared__ float cb[VQ_K];
        cb[threadIdx.x] = codebook[(size_t)(v - VQ_START) * VQ_K + threadIdx.x];
        __syncthreads();
#pragma unroll
        for (int j = 0; j < 8; ++j) {
            const int n = threadIdx.x + 256 * j;
            const float* wrow = proj_w + (size_t)n * VQ_K;
            float s = 0.f;
#pragma unroll 4
            for (int k = 0; k < VQ_K; k += 4) {
                const float4 w4 = *(const float4*)(wrow + k);
                s += w4.x * cb[k] + w4.y * cb[k + 1] + w4.z * cb[k + 2] + w4.w * cb[k + 3];
            }
            orow[n] = s;   // coalesced across threads
        }
        return;
    }

    const float* src = nullptr;
    if (v >= 0 && v < ATO)                  src = token_emb + (size_t)v * EMB_D;
    else if (v >= ATO && v < ATO + SCO)     src = numbers_emb + (size_t)(v - ATO) * EMB_D;
    else if (v >= ATO + SCO && v < VQ_START) src = added_emb + (size_t)(v - ATO - SCO) * EMB_D;

    float4* d4 = (float4*)orow;
    if (src) {
        const float4* s4 = (const float4*)src;
        d4[threadIdx.x]       = s4[threadIdx.x];
        d4[threadIdx.x + 256] = s4[threadIdx.x + 256];
    } else {
        const float4 z = make_float4(0.f, 0.f, 0.f, 0.f);
        d4[threadIdx.x]       = z;
        d4[threadIdx.x + 256] = z;
    }
}

// ---------------------------------------------------------------------------
extern "C" void kernel_launch(void* const* d_in, const int* in_sizes, int n_in,
                              void* d_out, int out_size, void* d_ws, size_t ws_size,
                              hipStream_t stream) {
    const int*   x           = (const int*)d_in[0];
    const float* token_emb   = (const float*)d_in[1];
    const float* added_emb   = (const float*)d_in[2];
    const float* numbers_emb = (const float*)d_in[3];
    const float* codebook    = (const float*)d_in[4];
    const float* proj_w      = (const float*)d_in[5];
    float*       out         = (float*)d_out;

    const int n_tok = in_sizes[0];   // B*S = 32768

    // workspace layout: [count 16B][img_list n_tok*4][cb_hi][cb_lo][pw_hi][pw_lo]
    const size_t list_bytes = (size_t)n_tok * sizeof(unsigned int);
    const size_t conv_off   = (16 + list_bytes + 63) & ~(size_t)63;
    const size_t cb_bytes   = (size_t)VQ_VOCAB * VQ_K * sizeof(bf16_t);  // 8 MiB
    const size_t pw_bytes   = (size_t)EMB_D * VQ_K * sizeof(bf16_t);     // 1 MiB
    const size_t ws_needed  = conv_off + 2 * cb_bytes + 2 * pw_bytes;

    if (d_ws == nullptr || ws_size < ws_needed) {
        // workspace too small: fused, workspace-free fallback
        fused_fallback_kernel<<<n_tok, 256, 0, stream>>>(
            x, token_emb, added_emb, numbers_emb, codebook, proj_w, out);
        return;
    }

    int* img_count         = (int*)d_ws;
    unsigned int* img_list = (unsigned int*)((char*)d_ws + 16);
    bf16_t* cb_hi = (bf16_t*)((char*)d_ws + conv_off);
    bf16_t* cb_lo = (bf16_t*)((char*)d_ws + conv_off + cb_bytes);
    bf16_t* pw_hi = (bf16_t*)((char*)d_ws + conv_off + 2 * cb_bytes);
    bf16_t* pw_lo = (bf16_t*)((char*)d_ws + conv_off + 2 * cb_bytes + pw_bytes);

    // d_ws is re-poisoned to 0xAA before every call: zero the atomic counter
    // with a capture-safe kernel (no runtime memset APIs inside capture).
    zero_count_kernel<<<1, 64, 0, stream>>>(img_count);

    prep_kernel<<<PREP_COMPACT_BLOCKS + PREP_CONV_CB + PREP_CONV_PW, 256, 0, stream>>>(
        x, n_tok, img_count, img_list, codebook, proj_w, cb_hi, cb_lo, pw_hi, pw_lo);

    const int gemm_m     = (n_tok + 63) / 64;        // static worst-case grid
    const int gemm_total = gemm_m * NSPLIT;
    const int copy_blocks = (n_tok + 3) / 4;         // one wave per token
    mega_kernel<<<gemm_total + copy_blocks, 256, 0, stream>>>(
        x, token_emb, added_emb, numbers_emb,
        cb_hi, cb_lo, pw_hi, pw_lo,
        out, img_count, img_list, n_tok, gemm_total);
}